// Round 1
// baseline (2973.948 us; speedup 1.0000x reference)
//
#include <hip/hip_runtime.h>

// PhysicsGraphFusion: B=1024, N=7, D=1024
// Outputs (flat, in order): fused (B*D), updated (B*N*D), imp (B*N),
// attn (B*N*N), phys (1), align (1)

#define BDIM 1024
#define NNODE 7

__constant__ float c_adj[49] = {
    1,1,0,0,1,1,1,
    1,1,1,1,1,1,1,
    0,1,1,0,1,0,1,
    0,1,0,1,1,1,1,
    1,1,1,1,1,1,1,
    1,1,0,1,1,1,1,
    1,1,1,1,1,1,1};

__device__ __forceinline__ float gelu_f(float x) {
    return 0.5f * x * (1.0f + erff(x * 0.7071067811865476f));
}

// Generic tiled SGEMM: C[M x 1024] = epilogue(Acat[M x K] @ W[K x 1024])
// Acat columns [0,1024) come from A1, [1024,2048) from A2 (virtual concat).
// Row mapping modes: 0: row r -> r ; 1: r -> r*7+6 (ctx rows of nodes) ;
//                    2: r -> (r/7)*7+6 (ctx broadcast of updated).
// Epilogue: +bias (if non-null), gelu (if act), +resid[r*1024+c] (if non-null).
__global__ __launch_bounds__(256) void gemm64(
    const float* __restrict__ A1, int a1Mode,
    const float* __restrict__ A2, int a2Mode,
    const float* __restrict__ W,
    const float* __restrict__ bias,
    const float* __restrict__ resid,
    float* __restrict__ C,
    int K, int act)
{
    __shared__ float As[16][68];   // stride 68: 16B-aligned rows, 2-way max bank conflict
    __shared__ float Bs[16][64];
    const int tid = threadIdx.x;
    const int tx = tid & 15, ty = tid >> 4;
    const int row0 = blockIdx.y * 64;
    const int col0 = blockIdx.x * 64;
    float acc[4][4] = {};
    const int kk_a = tid & 15;   // k-index for A loads
    const int m_a  = tid >> 4;   // 0..15 row group
    const int c_b  = tid & 63;
    const int k_b  = tid >> 6;   // 0..3

    for (int k0 = 0; k0 < K; k0 += 16) {
        const float* src; int mode; int colbase;
        if (k0 < 1024) { src = A1; mode = a1Mode; colbase = k0; }
        else           { src = A2; mode = a2Mode; colbase = k0 - 1024; }
        #pragma unroll
        for (int s = 0; s < 4; ++s) {
            int mm = m_a + s * 16;
            int r = row0 + mm;
            int rr;
            if (mode == 0)      rr = r;
            else if (mode == 1) rr = r * 7 + 6;
            else                rr = r - (r % 7) + 6;
            As[kk_a][mm] = src[(size_t)rr * 1024 + colbase + kk_a];
        }
        #pragma unroll
        for (int s = 0; s < 4; ++s) {
            int kk = k_b + s * 4;
            Bs[kk][c_b] = W[(size_t)(k0 + kk) * 1024 + col0 + c_b];
        }
        __syncthreads();
        #pragma unroll
        for (int kk = 0; kk < 16; ++kk) {
            float4 a4 = *(const float4*)(&As[kk][ty * 4]);
            float4 b4 = *(const float4*)(&Bs[kk][tx * 4]);
            acc[0][0] += a4.x * b4.x; acc[0][1] += a4.x * b4.y;
            acc[0][2] += a4.x * b4.z; acc[0][3] += a4.x * b4.w;
            acc[1][0] += a4.y * b4.x; acc[1][1] += a4.y * b4.y;
            acc[1][2] += a4.y * b4.z; acc[1][3] += a4.y * b4.w;
            acc[2][0] += a4.z * b4.x; acc[2][1] += a4.z * b4.y;
            acc[2][2] += a4.z * b4.z; acc[2][3] += a4.z * b4.w;
            acc[3][0] += a4.w * b4.x; acc[3][1] += a4.w * b4.y;
            acc[3][2] += a4.w * b4.z; acc[3][3] += a4.w * b4.w;
        }
        __syncthreads();
    }
    #pragma unroll
    for (int i = 0; i < 4; ++i) {
        int r = row0 + ty * 4 + i;
        #pragma unroll
        for (int j = 0; j < 4; ++j) {
            int c = col0 + tx * 4 + j;
            float vv = acc[i][j];
            if (bias)  vv += bias[c];
            if (act)   vv = gelu_f(vv);
            if (resid) vv += resid[(size_t)r * 1024 + c];
            C[(size_t)r * 1024 + c] = vv;
        }
    }
}

// One block per (b,n): edge MLP + logits + softmax + messages.
// msg may alias la (each block reads only its own la row, into registers first).
__global__ __launch_bounds__(256) void attn_msg(
    const float* __restrict__ q, const float* __restrict__ k,
    const float* __restrict__ v,
    const float* __restrict__ la, const float* __restrict__ rb,
    const float* __restrict__ cc,   // nodes[:, -1] @ Wc + be1
    const float* __restrict__ We2, const float* __restrict__ be2,
    float* __restrict__ attn_out, float* __restrict__ msg)
{
    const int bn = blockIdx.x;
    const int b = bn / 7, n = bn % 7;
    const int tid = threadIdx.x;
    const int lane = tid & 63, wv = tid >> 6;
    __shared__ float red[8];
    __shared__ float sm[7];

    float qv[4], lav[4], ccv[4], wev[4];
    #pragma unroll
    for (int j = 0; j < 4; ++j) {
        int d = tid + j * 256;
        qv[j]  = q[(size_t)bn * 1024 + d];
        lav[j] = la[(size_t)bn * 1024 + d];
        ccv[j] = cc[(size_t)b * 1024 + d];
        wev[j] = We2[d];
    }
    for (int m = 0; m < 7; ++m) {
        const float* krow  = k  + (size_t)(b * 7 + m) * 1024;
        const float* rbrow = rb + (size_t)(b * 7 + m) * 1024;
        float s1 = 0.f, s2 = 0.f;
        #pragma unroll
        for (int j = 0; j < 4; ++j) {
            int d = tid + j * 256;
            s1 += qv[j] * krow[d];
            s2 += gelu_f(lav[j] + rbrow[d] + ccv[j]) * wev[j];
        }
        #pragma unroll
        for (int off = 32; off > 0; off >>= 1) {
            s1 += __shfl_down(s1, off);
            s2 += __shfl_down(s2, off);
        }
        if (lane == 0) { red[wv * 2] = s1; red[wv * 2 + 1] = s2; }
        __syncthreads();
        if (tid == 0) {
            float d1 = red[0] + red[2] + red[4] + red[6];
            float d2 = red[1] + red[3] + red[5] + red[7];
            sm[m] = d1 * (1.0f / 32.0f) + d2 + be2[0]
                  + (c_adj[n * 7 + m] - 1.0f) * 10000.0f;
        }
        __syncthreads();
    }
    if (tid == 0) {
        float mx = sm[0];
        #pragma unroll
        for (int m = 1; m < 7; ++m) mx = fmaxf(mx, sm[m]);
        float e[7], s = 0.f;
        #pragma unroll
        for (int m = 0; m < 7; ++m) { e[m] = expf(sm[m] - mx); s += e[m]; }
        float inv = 1.0f / s;
        #pragma unroll
        for (int m = 0; m < 7; ++m) {
            float w = e[m] * inv;
            sm[m] = w;
            attn_out[(size_t)bn * 7 + m] = w;
        }
    }
    __syncthreads();
    float w[7];
    #pragma unroll
    for (int m = 0; m < 7; ++m) w[m] = sm[m];
    #pragma unroll
    for (int j = 0; j < 4; ++j) {
        int d = tid + j * 256;
        float s = 0.f;
        #pragma unroll
        for (int m = 0; m < 7; ++m) s += w[m] * v[(size_t)(b * 7 + m) * 1024 + d];
        msg[(size_t)bn * 1024 + d] = s;
    }
}

// imp_logits[r] = dot(H[r,:], w2) + b2[0]
__global__ __launch_bounds__(256) void row_dot(
    const float* __restrict__ H, const float* __restrict__ w2,
    const float* __restrict__ b2, float* __restrict__ out)
{
    const int r = blockIdx.x;
    const int tid = threadIdx.x;
    const int lane = tid & 63, wv = tid >> 6;
    __shared__ float red[4];
    float s = 0.f;
    #pragma unroll
    for (int j = 0; j < 4; ++j) {
        int d = tid + j * 256;
        s += H[(size_t)r * 1024 + d] * w2[d];
    }
    #pragma unroll
    for (int off = 32; off > 0; off >>= 1) s += __shfl_down(s, off);
    if (lane == 0) red[wv] = s;
    __syncthreads();
    if (tid == 0) out[r] = red[0] + red[1] + red[2] + red[3] + b2[0];
}

// per-b: softmax over N, cap/redistribute, write imp; fused = sum_n imp*updated
__global__ __launch_bounds__(256) void imp_fused_k(
    const float* __restrict__ logits, const float* __restrict__ upd,
    float* __restrict__ imp_out, float* __restrict__ fused_out)
{
    const int b = blockIdx.x;
    const int tid = threadIdx.x;
    __shared__ float w[7];
    if (tid == 0) {
        float l[7], e[7];
        float mx = -1e30f;
        for (int i = 0; i < 7; ++i) { l[i] = logits[b * 7 + i]; mx = fmaxf(mx, l[i]); }
        float s = 0.f;
        for (int i = 0; i < 7; ++i) { e[i] = expf(l[i] - mx); s += e[i]; }
        float inv = 1.0f / s;
        float imp[7];
        for (int i = 0; i < 7; ++i) imp[i] = e[i] * inv;
        const float cap[7] = {1.f, 1.f, 1.f, 0.26f, 1.f, 1.f, 0.24f};  // VIB=3:0.26, CTX=6:0.24
        const float fr[7]  = {1.f, 1.f, 1.f, 0.f,   1.f, 1.f, 0.f};
        float capped[7], capsum = 0.f, fmass = 0.f;
        for (int i = 0; i < 7; ++i) {
            capped[i] = fminf(imp[i], cap[i]);
            capsum += capped[i];
            fmass += imp[i] * fr[i];
        }
        float residual = fmaxf(1.0f - capsum, 0.0f);
        float redis[7], rs = 0.f;
        for (int i = 0; i < 7; ++i) {
            float fs = (fmass > 1e-6f) ? imp[i] * fr[i] / fmaxf(fmass, 1e-6f)
                                       : fr[i] * 0.2f;   // uniform = free/5
            redis[i] = capped[i] + fs * residual;
            rs += redis[i];
        }
        float invr = 1.0f / fmaxf(rs, 1e-6f);
        for (int i = 0; i < 7; ++i) {
            float wi = redis[i] * invr;
            w[i] = wi;
            imp_out[b * 7 + i] = wi;
        }
    }
    __syncthreads();
    float wr[7];
    #pragma unroll
    for (int i = 0; i < 7; ++i) wr[i] = w[i];
    #pragma unroll
    for (int j = 0; j < 4; ++j) {
        int d = tid + j * 256;
        float s = 0.f;
        #pragma unroll
        for (int nn2 = 0; nn2 < 7; ++nn2)
            s += wr[nn2] * upd[(size_t)(b * 7 + nn2) * 1024 + d];
        fused_out[(size_t)b * 1024 + d] = s;
    }
}

__global__ void zero_acc(float* a) { if (threadIdx.x < 4) a[threadIdx.x] = 0.f; }

// per-b: 28 pairwise dots + 7 fused dots + fused norm; accumulate loss partials
__global__ __launch_bounds__(256) void physics_k(
    const float* __restrict__ upd, const float* __restrict__ fused,
    float* __restrict__ accums)
{
    const int b = blockIdx.x;
    const int tid = threadIdx.x;
    const int lane = tid & 63, wv = tid >> 6;
    __shared__ float u[7][1024];
    __shared__ float f[1024];
    __shared__ float wred[4][36];
    for (int idx = tid; idx < 7 * 1024; idx += 256)
        u[idx >> 10][idx & 1023] = upd[(size_t)b * 7168 + idx];
    for (int d = tid; d < 1024; d += 256)
        f[d] = fused[(size_t)b * 1024 + d];
    __syncthreads();

    float vals[36];
    #pragma unroll
    for (int i = 0; i < 36; ++i) vals[i] = 0.f;
    for (int d = tid; d < 1024; d += 256) {
        float x[7];
        #pragma unroll
        for (int n = 0; n < 7; ++n) x[n] = u[n][d];
        float fv = f[d];
        int idx = 0;
        #pragma unroll
        for (int n = 0; n < 7; ++n) {
            #pragma unroll
            for (int m = n; m < 7; ++m) vals[idx++] += x[n] * x[m];
        }
        #pragma unroll
        for (int n = 0; n < 7; ++n) vals[28 + n] += x[n] * fv;
        vals[35] += fv * fv;
    }
    #pragma unroll
    for (int i = 0; i < 36; ++i) {
        float s = vals[i];
        #pragma unroll
        for (int off = 32; off > 0; off >>= 1) s += __shfl_down(s, off);
        if (lane == 0) wred[wv][i] = s;
    }
    __syncthreads();
    if (tid == 0) {
        float tv[36];
        for (int i = 0; i < 36; ++i)
            tv[i] = wred[0][i] + wred[1][i] + wred[2][i] + wred[3][i];
        auto didx = [](int n, int m) -> int {
            if (n > m) { int t = n; n = m; m = t; }
            return n * 7 - n * (n - 1) / 2 + (m - n);
        };
        float norms[7];
        for (int n = 0; n < 7; ++n) norms[n] = sqrtf(tv[didx(n, n)]);
        float e = 0.f, nl = 0.f;
        for (int n = 0; n < 7; ++n)
            for (int m = 0; m < 7; ++m) {
                float cos_ = tv[didx(n, m)] / fmaxf(norms[n] * norms[m], 1e-8f);
                float adj = c_adj[n * 7 + m];
                e += (1.0f - cos_) * adj;
                if (adj == 0.0f && n != m) nl += fmaxf(cos_ - 0.35f, 0.0f);
            }
        float fnorm = sqrtf(tv[35]);
        float al = 0.f;
        for (int n = 0; n < 7; ++n) {
            float cosn = tv[28 + n] /
                         (fmaxf(norms[n], 1e-12f) * fmaxf(fnorm, 1e-12f));
            al += 1.0f - cosn;
        }
        atomicAdd(&accums[0], e);
        atomicAdd(&accums[1], nl);
        atomicAdd(&accums[2], al);
    }
}

__global__ void finalize_k(const float* __restrict__ a,
                           float* __restrict__ phys_o,
                           float* __restrict__ align_o)
{
    // phys = edge_sum/ADJ.sum(41) + 0.5 * non_sum/non_mask.sum(8); align = mean
    phys_o[0]  = a[0] / 41.0f + 0.5f * (a[1] / 8.0f);
    align_o[0] = a[2] * (1.0f / 7168.0f);
}

extern "C" void kernel_launch(void* const* d_in, const int* in_sizes, int n_in,
                              void* d_out, int out_size, void* d_ws, size_t ws_size,
                              hipStream_t stream)
{
    const float* nodes = (const float*)d_in[0];
    const float* Wq  = (const float*)d_in[1];
    const float* bq  = (const float*)d_in[2];
    const float* Wk  = (const float*)d_in[3];
    const float* bk  = (const float*)d_in[4];
    const float* Wv  = (const float*)d_in[5];
    const float* bv  = (const float*)d_in[6];
    const float* We1 = (const float*)d_in[7];
    const float* be1 = (const float*)d_in[8];
    const float* We2 = (const float*)d_in[9];
    const float* be2 = (const float*)d_in[10];
    const float* Wu1 = (const float*)d_in[11];
    const float* bu1 = (const float*)d_in[12];
    const float* Wu2 = (const float*)d_in[13];
    const float* bu2 = (const float*)d_in[14];
    const float* Wi1 = (const float*)d_in[15];
    const float* bi1 = (const float*)d_in[16];
    const float* Wi2 = (const float*)d_in[17];
    const float* bi2 = (const float*)d_in[18];

    float* out = (float*)d_out;
    float* fused_o = out;                            // 1,048,576
    float* upd_o   = out + 1048576;                  // 7,340,032
    float* imp_o   = out + 1048576 + 7340032;        // 7,168
    float* attn_o  = imp_o + 7168;                   // 50,176
    float* phys_o  = attn_o + 50176;                 // 1
    float* align_o = phys_o + 1;                     // 1

    float* ws = (float*)d_ws;
    const size_t BIG = 7340032;  // B*N*D
    float* q   = ws;
    float* kk  = ws + BIG;
    float* v   = ws + 2 * BIG;
    float* la  = ws + 3 * BIG;   // becomes messages after attn_msg
    float* rb  = ws + 4 * BIG;   // becomes h (MLP hidden) after attn_msg
    float* cc  = ws + 5 * BIG;   // 1,048,576
    float* il  = cc + 1048576;   // imp logits: 7168
    float* acc = il + 7168;      // 4 accumulators

    dim3 blk(256);
    dim3 gBig(16, 112);   // 1024/64 x 7168/64
    dim3 gCc(16, 16);     // 1024/64 x 1024/64

    // q, k, v, la, rb
    gemm64<<<gBig, blk, 0, stream>>>(nodes, 0, nullptr, 0, Wq, bq, nullptr, q, 1024, 0);
    gemm64<<<gBig, blk, 0, stream>>>(nodes, 0, nullptr, 0, Wk, bk, nullptr, kk, 1024, 0);
    gemm64<<<gBig, blk, 0, stream>>>(nodes, 0, nullptr, 0, Wv, bv, nullptr, v, 1024, 0);
    gemm64<<<gBig, blk, 0, stream>>>(nodes, 0, nullptr, 0, We1, nullptr, nullptr, la, 1024, 0);
    gemm64<<<gBig, blk, 0, stream>>>(nodes, 0, nullptr, 0, We1 + 1048576, nullptr, nullptr, rb, 1024, 0);
    // cc = nodes[:, -1] @ Wc + be1   (be1 folded here)
    gemm64<<<gCc, blk, 0, stream>>>(nodes, 1, nullptr, 0, We1 + 2097152, be1, nullptr, cc, 1024, 0);
    // attention + messages (msg overwrites la)
    attn_msg<<<dim3(7168), blk, 0, stream>>>(q, kk, v, la, rb, cc, We2, be2, attn_o, la);
    // h_u = gelu([nodes | msg] @ Wu1 + bu1)  -> rb buffer
    gemm64<<<gBig, blk, 0, stream>>>(nodes, 0, la, 0, Wu1, bu1, nullptr, rb, 2048, 1);
    // updated = h_u @ Wu2 + bu2 + nodes -> d_out
    gemm64<<<gBig, blk, 0, stream>>>(rb, 0, nullptr, 0, Wu2, bu2, nodes, upd_o, 1024, 0);
    // h_i = gelu([updated | ctx-bcast(updated)] @ Wi1 + bi1) -> rb buffer
    gemm64<<<gBig, blk, 0, stream>>>(upd_o, 0, upd_o, 2, Wi1, bi1, nullptr, rb, 2048, 1);
    // imp_logits
    row_dot<<<dim3(7168), blk, 0, stream>>>(rb, Wi2, bi2, il);
    // imp softmax + cap + fused
    imp_fused_k<<<dim3(1024), blk, 0, stream>>>(il, upd_o, imp_o, fused_o);
    // losses
    zero_acc<<<1, 64, 0, stream>>>(acc);
    physics_k<<<dim3(1024), blk, 0, stream>>>(upd_o, fused_o, acc);
    finalize_k<<<1, 1, 0, stream>>>(acc, phys_o, align_o);
}

// Round 2
// 750.138 us; speedup vs baseline: 3.9645x; 3.9645x over previous
//
#include <hip/hip_runtime.h>
#include <hip/hip_bf16.h>

// PhysicsGraphFusion: B=1024, N=7, D=1024
// Outputs (flat): fused (B*D), updated (B*N*D), imp (B*N), attn (B*N*N), phys (1), align (1)

typedef __attribute__((ext_vector_type(8))) short bf16x8;
typedef __attribute__((ext_vector_type(4))) float f32x4;

__constant__ float c_adj[49] = {
    1,1,0,0,1,1,1,
    1,1,1,1,1,1,1,
    0,1,1,0,1,0,1,
    0,1,0,1,1,1,1,
    1,1,1,1,1,1,1,
    1,1,0,1,1,1,1,
    1,1,1,1,1,1,1};

__device__ __forceinline__ float gelu_f(float x) {
    return 0.5f * x * (1.0f + erff(x * 0.7071067811865476f));
}
__device__ __forceinline__ float b2f(unsigned short u) {
    unsigned int x = ((unsigned int)u) << 16;
    union { unsigned int i; float f; } c; c.i = x; return c.f;
}
__device__ __forceinline__ unsigned short f2b(float f) {
    __hip_bfloat16 h = __float2bfloat16(f);
    union { __hip_bfloat16 b; unsigned short u; } c; c.b = h; return c.u;
}

__device__ __forceinline__ void gload_lds16(const void* g, void* l) {
    __builtin_amdgcn_global_load_lds(
        (const __attribute__((address_space(1))) unsigned int*)g,
        (__attribute__((address_space(3))) unsigned int*)l, 16, 0, 0);
}

// ---------------------------------------------------------------------------
// bf16 MFMA GEMM (m97 structure): C[M x 1024] = epi(Acat[M x K] @ WT^T)
// A row-major bf16 (row stride 1024); WT = W^T, [1024 x K] bf16, row stride ldw.
// Acat cols [0,1024) from A1, [1024,2048) from A2. a2Mode: 0 normal,
// 2: row r -> r - r%7 + 6 (ctx broadcast). Epilogue: +bias, gelu, +resid(fp32).
// Outputs: Cf (fp32, optional), Cb (bf16, optional).
// ---------------------------------------------------------------------------
__global__ __launch_bounds__(256) void gemm_bf16(
    const unsigned short* __restrict__ A1, int a1Mode,
    const unsigned short* __restrict__ A2, int a2Mode,
    const unsigned short* __restrict__ WT, int ldw,
    const float* __restrict__ bias,
    const float* __restrict__ resid,
    float* __restrict__ Cf,
    unsigned short* __restrict__ Cb,
    int K, int act)
{
    __shared__ short As[128 * 32];   // [m][k] bf16, stride 32
    __shared__ short Bs[128 * 32];   // [n][k] bf16, stride 32
    const int tid = threadIdx.x;
    const int lane = tid & 63;
    const int w = tid >> 6;
    const int wr = (w >> 1) * 64;    // wave row offset in tile
    const int wc = (w & 1) * 64;     // wave col offset in tile
    const int row0 = blockIdx.y * 128;
    const int col0 = blockIdx.x * 128;
    const int fr = lane & 15;        // fragment row/col
    const int fk = (lane >> 4) * 8;  // fragment k offset

    f32x4 acc[4][4] = {};

    for (int k0 = 0; k0 < K; k0 += 32) {
        const unsigned short* srcA; int mode; int kbase;
        if (k0 < 1024) { srcA = A1; mode = a1Mode; kbase = k0; }
        else           { srcA = A2; mode = a2Mode; kbase = k0 - 1024; }
        // stage A tile: 512 chunks of 16B (8 bf16): chunk c -> m=c>>2, kc=(c&3)*8
        #pragma unroll
        for (int rnd = 0; rnd < 2; ++rnd) {
            int c = rnd * 256 + tid;
            int m = c >> 2, kc = (c & 3) * 8;
            int r = row0 + m;
            int rr = (mode == 2) ? (r - r % 7 + 6) : r;
            gload_lds16(srcA + (size_t)rr * 1024 + kbase + kc, &As[c * 8]);
        }
        // stage B tile: WT rows col0..col0+128
        #pragma unroll
        for (int rnd = 0; rnd < 2; ++rnd) {
            int c = rnd * 256 + tid;
            int n = c >> 2, kc = (c & 3) * 8;
            gload_lds16(WT + (size_t)(col0 + n) * ldw + k0 + kc, &Bs[c * 8]);
        }
        __syncthreads();
        bf16x8 af[4], bf_[4];
        #pragma unroll
        for (int i = 0; i < 4; ++i)
            af[i] = *(const bf16x8*)(&As[(wr + i * 16 + fr) * 32 + fk]);
        #pragma unroll
        for (int j = 0; j < 4; ++j)
            bf_[j] = *(const bf16x8*)(&Bs[(wc + j * 16 + fr) * 32 + fk]);
        #pragma unroll
        for (int i = 0; i < 4; ++i)
            #pragma unroll
            for (int j = 0; j < 4; ++j)
                acc[i][j] = __builtin_amdgcn_mfma_f32_16x16x32_bf16(
                    af[i], bf_[j], acc[i][j], 0, 0, 0);
        __syncthreads();
    }

    // C/D layout: col = lane&15, row = (lane>>4)*4 + reg  [m89/m91 verified]
    const int qrow = (lane >> 4) * 4;
    const int qcol = lane & 15;
    #pragma unroll
    for (int i = 0; i < 4; ++i) {
        int rbase = row0 + wr + i * 16 + qrow;
        #pragma unroll
        for (int j = 0; j < 4; ++j) {
            int c = col0 + wc + j * 16 + qcol;
            float bv = bias ? bias[c] : 0.0f;
            #pragma unroll
            for (int reg = 0; reg < 4; ++reg) {
                int r = rbase + reg;
                float vv = acc[i][j][reg] + bv;
                if (act) vv = gelu_f(vv);
                if (resid) vv += resid[(size_t)r * 1024 + c];
                if (Cf) Cf[(size_t)r * 1024 + c] = vv;
                if (Cb) Cb[(size_t)r * 1024 + c] = f2b(vv);
            }
        }
    }
}

// ---------------------------------------------------------------------------
// fp32 tiled GEMM (kept only for the small cc = nodes[:,-1] @ Wc + be1)
// ---------------------------------------------------------------------------
__global__ __launch_bounds__(256) void gemm64(
    const float* __restrict__ A1, int a1Mode,
    const float* __restrict__ W,
    const float* __restrict__ bias,
    float* __restrict__ C, int K)
{
    __shared__ float As[16][68];
    __shared__ float Bs[16][64];
    const int tid = threadIdx.x;
    const int tx = tid & 15, ty = tid >> 4;
    const int row0 = blockIdx.y * 64;
    const int col0 = blockIdx.x * 64;
    float acc[4][4] = {};
    const int kk_a = tid & 15;
    const int m_a  = tid >> 4;
    const int c_b  = tid & 63;
    const int k_b  = tid >> 6;

    for (int k0 = 0; k0 < K; k0 += 16) {
        #pragma unroll
        for (int s = 0; s < 4; ++s) {
            int mm = m_a + s * 16;
            int r = row0 + mm;
            int rr = (a1Mode == 1) ? (r * 7 + 6) : r;
            As[kk_a][mm] = A1[(size_t)rr * 1024 + k0 + kk_a];
        }
        #pragma unroll
        for (int s = 0; s < 4; ++s) {
            int kk = k_b + s * 4;
            Bs[kk][c_b] = W[(size_t)(k0 + kk) * 1024 + col0 + c_b];
        }
        __syncthreads();
        #pragma unroll
        for (int kk = 0; kk < 16; ++kk) {
            float4 a4 = *(const float4*)(&As[kk][ty * 4]);
            float4 b4 = *(const float4*)(&Bs[kk][tx * 4]);
            acc[0][0] += a4.x * b4.x; acc[0][1] += a4.x * b4.y;
            acc[0][2] += a4.x * b4.z; acc[0][3] += a4.x * b4.w;
            acc[1][0] += a4.y * b4.x; acc[1][1] += a4.y * b4.y;
            acc[1][2] += a4.y * b4.z; acc[1][3] += a4.y * b4.w;
            acc[2][0] += a4.z * b4.x; acc[2][1] += a4.z * b4.y;
            acc[2][2] += a4.z * b4.z; acc[2][3] += a4.z * b4.w;
            acc[3][0] += a4.w * b4.x; acc[3][1] += a4.w * b4.y;
            acc[3][2] += a4.w * b4.z; acc[3][3] += a4.w * b4.w;
        }
        __syncthreads();
    }
    #pragma unroll
    for (int i = 0; i < 4; ++i) {
        int r = row0 + ty * 4 + i;
        #pragma unroll
        for (int j = 0; j < 4; ++j) {
            int c = col0 + tx * 4 + j;
            C[(size_t)r * 1024 + c] = acc[i][j] + (bias ? bias[c] : 0.0f);
        }
    }
}

// fp32 -> bf16 elementwise cast (n divisible by 1024)
__global__ __launch_bounds__(256) void cast_f2b(
    const float* __restrict__ in, unsigned short* __restrict__ out, int n)
{
    int i = (blockIdx.x * 256 + threadIdx.x) * 4;
    if (i >= n) return;
    float4 v = *(const float4*)(in + i);
    ushort4 o;
    o.x = f2b(v.x); o.y = f2b(v.y); o.z = f2b(v.z); o.w = f2b(v.w);
    *(ushort4*)(out + i) = o;
}

// transpose + cast: W fp32 [R x 1024] -> WT bf16 [1024 x R]
__global__ __launch_bounds__(256) void tcast(
    const float* __restrict__ W, unsigned short* __restrict__ WT, int R)
{
    __shared__ float t[32][33];
    const int ct = blockIdx.x * 32;   // col tile of W
    const int rt = blockIdx.y * 32;   // row tile of W
    const int tx = threadIdx.x & 31, ty = threadIdx.x >> 5;
    #pragma unroll
    for (int s = 0; s < 4; ++s)
        t[ty + s * 8][tx] = W[(size_t)(rt + ty + s * 8) * 1024 + ct + tx];
    __syncthreads();
    #pragma unroll
    for (int s = 0; s < 4; ++s)
        WT[(size_t)(ct + ty + s * 8) * R + rt + tx] = f2b(t[tx][ty + s * 8]);
}

// ---------------------------------------------------------------------------
// One block per (b,n): edge MLP + logits + softmax + messages (bf16 in/out)
// ---------------------------------------------------------------------------
__global__ __launch_bounds__(256) void attn_msg_b(
    const unsigned short* __restrict__ q, const unsigned short* __restrict__ k,
    const unsigned short* __restrict__ v,
    const unsigned short* __restrict__ la, const unsigned short* __restrict__ rb,
    const float* __restrict__ cc,   // nodes[:,-1] @ Wc + be1 (fp32)
    const float* __restrict__ We2, const float* __restrict__ be2,
    float* __restrict__ attn_out, unsigned short* __restrict__ msg)
{
    const int bn = blockIdx.x;
    const int b = bn / 7, n = bn % 7;
    const int tid = threadIdx.x;
    const int lane = tid & 63, wv = tid >> 6;
    const int d0 = tid * 4;
    __shared__ float red[8];
    __shared__ float sm[7];

    float qv[4], lav[4], ccv[4], wev[4];
    {
        ushort4 q4 = *(const ushort4*)(q + (size_t)bn * 1024 + d0);
        ushort4 l4 = *(const ushort4*)(la + (size_t)bn * 1024 + d0);
        float4 c4 = *(const float4*)(cc + (size_t)b * 1024 + d0);
        float4 w4 = *(const float4*)(We2 + d0);
        qv[0] = b2f(q4.x); qv[1] = b2f(q4.y); qv[2] = b2f(q4.z); qv[3] = b2f(q4.w);
        lav[0] = b2f(l4.x); lav[1] = b2f(l4.y); lav[2] = b2f(l4.z); lav[3] = b2f(l4.w);
        ccv[0] = c4.x; ccv[1] = c4.y; ccv[2] = c4.z; ccv[3] = c4.w;
        wev[0] = w4.x; wev[1] = w4.y; wev[2] = w4.z; wev[3] = w4.w;
    }
    for (int m = 0; m < 7; ++m) {
        ushort4 k4 = *(const ushort4*)(k  + (size_t)(b * 7 + m) * 1024 + d0);
        ushort4 r4 = *(const ushort4*)(rb + (size_t)(b * 7 + m) * 1024 + d0);
        float s1 = qv[0] * b2f(k4.x) + qv[1] * b2f(k4.y)
                 + qv[2] * b2f(k4.z) + qv[3] * b2f(k4.w);
        float s2 = gelu_f(lav[0] + b2f(r4.x) + ccv[0]) * wev[0]
                 + gelu_f(lav[1] + b2f(r4.y) + ccv[1]) * wev[1]
                 + gelu_f(lav[2] + b2f(r4.z) + ccv[2]) * wev[2]
                 + gelu_f(lav[3] + b2f(r4.w) + ccv[3]) * wev[3];
        #pragma unroll
        for (int off = 32; off > 0; off >>= 1) {
            s1 += __shfl_down(s1, off);
            s2 += __shfl_down(s2, off);
        }
        if (lane == 0) { red[wv * 2] = s1; red[wv * 2 + 1] = s2; }
        __syncthreads();
        if (tid == 0) {
            float d1 = red[0] + red[2] + red[4] + red[6];
            float d2 = red[1] + red[3] + red[5] + red[7];
            sm[m] = d1 * (1.0f / 32.0f) + d2 + be2[0]
                  + (c_adj[n * 7 + m] - 1.0f) * 10000.0f;
        }
        __syncthreads();
    }
    if (tid == 0) {
        float mx = sm[0];
        #pragma unroll
        for (int m = 1; m < 7; ++m) mx = fmaxf(mx, sm[m]);
        float e[7], s = 0.f;
        #pragma unroll
        for (int m = 0; m < 7; ++m) { e[m] = expf(sm[m] - mx); s += e[m]; }
        float inv = 1.0f / s;
        #pragma unroll
        for (int m = 0; m < 7; ++m) {
            float wgt = e[m] * inv;
            sm[m] = wgt;
            attn_out[(size_t)bn * 7 + m] = wgt;
        }
    }
    __syncthreads();
    float wr_[7];
    #pragma unroll
    for (int m = 0; m < 7; ++m) wr_[m] = sm[m];
    float s0 = 0.f, s1 = 0.f, s2 = 0.f, s3 = 0.f;
    #pragma unroll
    for (int m = 0; m < 7; ++m) {
        ushort4 v4 = *(const ushort4*)(v + (size_t)(b * 7 + m) * 1024 + d0);
        s0 += wr_[m] * b2f(v4.x); s1 += wr_[m] * b2f(v4.y);
        s2 += wr_[m] * b2f(v4.z); s3 += wr_[m] * b2f(v4.w);
    }
    ushort4 o;
    o.x = f2b(s0); o.y = f2b(s1); o.z = f2b(s2); o.w = f2b(s3);
    *(ushort4*)(msg + (size_t)bn * 1024 + d0) = o;
}

// imp_logits[r] = dot(H[r,:], w2) + b2[0]   (H bf16)
__global__ __launch_bounds__(256) void row_dot_b(
    const unsigned short* __restrict__ H, const float* __restrict__ w2,
    const float* __restrict__ b2, float* __restrict__ out)
{
    const int r = blockIdx.x;
    const int tid = threadIdx.x;
    const int lane = tid & 63, wv = tid >> 6;
    __shared__ float red[4];
    const int d0 = tid * 4;
    ushort4 h4 = *(const ushort4*)(H + (size_t)r * 1024 + d0);
    float4 w4 = *(const float4*)(w2 + d0);
    float s = b2f(h4.x) * w4.x + b2f(h4.y) * w4.y
            + b2f(h4.z) * w4.z + b2f(h4.w) * w4.w;
    #pragma unroll
    for (int off = 32; off > 0; off >>= 1) s += __shfl_down(s, off);
    if (lane == 0) red[wv] = s;
    __syncthreads();
    if (tid == 0) out[r] = red[0] + red[1] + red[2] + red[3] + b2[0];
}

// per-b: softmax over N, cap/redistribute, imp; fused = sum_n imp*updated
__global__ __launch_bounds__(256) void imp_fused_k(
    const float* __restrict__ logits, const float* __restrict__ upd,
    float* __restrict__ imp_out, float* __restrict__ fused_out)
{
    const int b = blockIdx.x;
    const int tid = threadIdx.x;
    __shared__ float w[7];
    if (tid == 0) {
        float l[7], e[7];
        float mx = -1e30f;
        for (int i = 0; i < 7; ++i) { l[i] = logits[b * 7 + i]; mx = fmaxf(mx, l[i]); }
        float s = 0.f;
        for (int i = 0; i < 7; ++i) { e[i] = expf(l[i] - mx); s += e[i]; }
        float inv = 1.0f / s;
        float imp[7];
        for (int i = 0; i < 7; ++i) imp[i] = e[i] * inv;
        const float cap[7] = {1.f, 1.f, 1.f, 0.26f, 1.f, 1.f, 0.24f};
        const float fr[7]  = {1.f, 1.f, 1.f, 0.f,   1.f, 1.f, 0.f};
        float capped[7], capsum = 0.f, fmass = 0.f;
        for (int i = 0; i < 7; ++i) {
            capped[i] = fminf(imp[i], cap[i]);
            capsum += capped[i];
            fmass += imp[i] * fr[i];
        }
        float residual = fmaxf(1.0f - capsum, 0.0f);
        float redis[7], rs = 0.f;
        for (int i = 0; i < 7; ++i) {
            float fs = (fmass > 1e-6f) ? imp[i] * fr[i] / fmaxf(fmass, 1e-6f)
                                       : fr[i] * 0.2f;
            redis[i] = capped[i] + fs * residual;
            rs += redis[i];
        }
        float invr = 1.0f / fmaxf(rs, 1e-6f);
        for (int i = 0; i < 7; ++i) {
            float wi = redis[i] * invr;
            w[i] = wi;
            imp_out[b * 7 + i] = wi;
        }
    }
    __syncthreads();
    float wr[7];
    #pragma unroll
    for (int i = 0; i < 7; ++i) wr[i] = w[i];
    #pragma unroll
    for (int j = 0; j < 4; ++j) {
        int d = tid + j * 256;
        float s = 0.f;
        #pragma unroll
        for (int nn2 = 0; nn2 < 7; ++nn2)
            s += wr[nn2] * upd[(size_t)(b * 7 + nn2) * 1024 + d];
        fused_out[(size_t)b * 1024 + d] = s;
    }
}

__global__ void zero_acc(float* a) { if (threadIdx.x < 4) a[threadIdx.x] = 0.f; }

__global__ __launch_bounds__(256) void physics_k(
    const float* __restrict__ upd, const float* __restrict__ fused,
    float* __restrict__ accums)
{
    const int b = blockIdx.x;
    const int tid = threadIdx.x;
    const int lane = tid & 63, wv = tid >> 6;
    __shared__ float u[7][1024];
    __shared__ float f[1024];
    __shared__ float wred[4][36];
    for (int idx = tid; idx < 7 * 1024; idx += 256)
        u[idx >> 10][idx & 1023] = upd[(size_t)b * 7168 + idx];
    for (int d = tid; d < 1024; d += 256)
        f[d] = fused[(size_t)b * 1024 + d];
    __syncthreads();

    float vals[36];
    #pragma unroll
    for (int i = 0; i < 36; ++i) vals[i] = 0.f;
    for (int d = tid; d < 1024; d += 256) {
        float x[7];
        #pragma unroll
        for (int n = 0; n < 7; ++n) x[n] = u[n][d];
        float fv = f[d];
        int idx = 0;
        #pragma unroll
        for (int n = 0; n < 7; ++n) {
            #pragma unroll
            for (int m = n; m < 7; ++m) vals[idx++] += x[n] * x[m];
        }
        #pragma unroll
        for (int n = 0; n < 7; ++n) vals[28 + n] += x[n] * fv;
        vals[35] += fv * fv;
    }
    #pragma unroll
    for (int i = 0; i < 36; ++i) {
        float s = vals[i];
        #pragma unroll
        for (int off = 32; off > 0; off >>= 1) s += __shfl_down(s, off);
        if (lane == 0) wred[wv][i] = s;
    }
    __syncthreads();
    if (tid == 0) {
        float tv[36];
        for (int i = 0; i < 36; ++i)
            tv[i] = wred[0][i] + wred[1][i] + wred[2][i] + wred[3][i];
        auto didx = [](int n, int m) -> int {
            if (n > m) { int t = n; n = m; m = t; }
            return n * 7 - n * (n - 1) / 2 + (m - n);
        };
        float norms[7];
        for (int n = 0; n < 7; ++n) norms[n] = sqrtf(tv[didx(n, n)]);
        float e = 0.f, nl = 0.f;
        for (int n = 0; n < 7; ++n)
            for (int m = 0; m < 7; ++m) {
                float cos_ = tv[didx(n, m)] / fmaxf(norms[n] * norms[m], 1e-8f);
                float adj = c_adj[n * 7 + m];
                e += (1.0f - cos_) * adj;
                if (adj == 0.0f && n != m) nl += fmaxf(cos_ - 0.35f, 0.0f);
            }
        float fnorm = sqrtf(tv[35]);
        float al = 0.f;
        for (int n = 0; n < 7; ++n) {
            float cosn = tv[28 + n] /
                         (fmaxf(norms[n], 1e-12f) * fmaxf(fnorm, 1e-12f));
            al += 1.0f - cosn;
        }
        atomicAdd(&accums[0], e);
        atomicAdd(&accums[1], nl);
        atomicAdd(&accums[2], al);
    }
}

__global__ void finalize_k(const float* __restrict__ a,
                           float* __restrict__ phys_o,
                           float* __restrict__ align_o)
{
    phys_o[0]  = a[0] / 41.0f + 0.5f * (a[1] / 8.0f);
    align_o[0] = a[2] * (1.0f / 7168.0f);
}

extern "C" void kernel_launch(void* const* d_in, const int* in_sizes, int n_in,
                              void* d_out, int out_size, void* d_ws, size_t ws_size,
                              hipStream_t stream)
{
    const float* nodes = (const float*)d_in[0];
    const float* Wq  = (const float*)d_in[1];
    const float* bq  = (const float*)d_in[2];
    const float* Wk  = (const float*)d_in[3];
    const float* bk  = (const float*)d_in[4];
    const float* Wv  = (const float*)d_in[5];
    const float* bv  = (const float*)d_in[6];
    const float* We1 = (const float*)d_in[7];
    const float* be1 = (const float*)d_in[8];
    const float* We2 = (const float*)d_in[9];
    const float* be2 = (const float*)d_in[10];
    const float* Wu1 = (const float*)d_in[11];
    const float* bu1 = (const float*)d_in[12];
    const float* Wu2 = (const float*)d_in[13];
    const float* bu2 = (const float*)d_in[14];
    const float* Wi1 = (const float*)d_in[15];
    const float* bi1 = (const float*)d_in[16];
    const float* Wi2 = (const float*)d_in[17];
    const float* bi2 = (const float*)d_in[18];

    float* out = (float*)d_out;
    float* fused_o = out;                            // 1,048,576
    float* upd_o   = out + 1048576;                  // 7,340,032
    float* imp_o   = out + 1048576 + 7340032;        // 7,168
    float* attn_o  = imp_o + 7168;                   // 50,176
    float* phys_o  = attn_o + 50176;                 // 1
    float* align_o = phys_o + 1;                     // 1

    const size_t BIG = 7340032;   // B*N*D
    const size_t MEG = 1048576;   // D*D
    char* p = (char*)d_ws;
    unsigned short* nodes_b = (unsigned short*)p; p += BIG * 2;
    unsigned short* qb      = (unsigned short*)p; p += BIG * 2;   // reused: h_u
    unsigned short* kb      = (unsigned short*)p; p += BIG * 2;   // reused: upd_b
    unsigned short* vb      = (unsigned short*)p; p += BIG * 2;   // reused: h_i
    unsigned short* lab     = (unsigned short*)p; p += BIG * 2;
    unsigned short* rbb     = (unsigned short*)p; p += BIG * 2;
    unsigned short* msgb    = (unsigned short*)p; p += BIG * 2;
    unsigned short* WqT     = (unsigned short*)p; p += MEG * 2;
    unsigned short* WkT     = (unsigned short*)p; p += MEG * 2;
    unsigned short* WvT     = (unsigned short*)p; p += MEG * 2;
    unsigned short* WeabT   = (unsigned short*)p; p += 2 * MEG * 2;  // [1024 x 2048]
    unsigned short* Wu1T    = (unsigned short*)p; p += 2 * MEG * 2;
    unsigned short* Wu2T    = (unsigned short*)p; p += MEG * 2;
    unsigned short* Wi1T    = (unsigned short*)p; p += 2 * MEG * 2;
    float* ccf = (float*)p; p += MEG * 4;
    float* il  = (float*)p; p += 7168 * 4;
    float* acc = (float*)p; p += 4 * 4;
    unsigned short* hub  = qb;
    unsigned short* updb = kb;
    unsigned short* hib  = vb;

    dim3 blk(256);
    dim3 gB(8, 56);     // 1024/128 x 7168/128

    // --- casts ---
    cast_f2b<<<dim3(7168), blk, 0, stream>>>(nodes, nodes_b, 7340032);
    tcast<<<dim3(32, 32), blk, 0, stream>>>(Wq, WqT, 1024);
    tcast<<<dim3(32, 32), blk, 0, stream>>>(Wk, WkT, 1024);
    tcast<<<dim3(32, 32), blk, 0, stream>>>(Wv, WvT, 1024);
    tcast<<<dim3(32, 64), blk, 0, stream>>>(We1, WeabT, 2048);   // Wa|Wb
    tcast<<<dim3(32, 64), blk, 0, stream>>>(Wu1, Wu1T, 2048);
    tcast<<<dim3(32, 32), blk, 0, stream>>>(Wu2, Wu2T, 1024);
    tcast<<<dim3(32, 64), blk, 0, stream>>>(Wi1, Wi1T, 2048);

    // cc = nodes[:,-1] @ Wc + be1 (fp32, small)
    gemm64<<<dim3(16, 16), blk, 0, stream>>>(nodes, 1, We1 + 2 * MEG, be1, ccf, 1024);

    // q/k/v/la/rb (bf16 out only)
    gemm_bf16<<<gB, blk, 0, stream>>>(nodes_b, 0, nullptr, 0, WqT, 1024, bq, nullptr, nullptr, qb, 1024, 0);
    gemm_bf16<<<gB, blk, 0, stream>>>(nodes_b, 0, nullptr, 0, WkT, 1024, bk, nullptr, nullptr, kb, 1024, 0);
    gemm_bf16<<<gB, blk, 0, stream>>>(nodes_b, 0, nullptr, 0, WvT, 1024, bv, nullptr, nullptr, vb, 1024, 0);
    gemm_bf16<<<gB, blk, 0, stream>>>(nodes_b, 0, nullptr, 0, WeabT, 2048, nullptr, nullptr, nullptr, lab, 1024, 0);
    gemm_bf16<<<gB, blk, 0, stream>>>(nodes_b, 0, nullptr, 0, WeabT + 1024, 2048, nullptr, nullptr, nullptr, rbb, 1024, 0);

    // attention + messages
    attn_msg_b<<<dim3(7168), blk, 0, stream>>>(qb, kb, vb, lab, rbb, ccf, We2, be2, attn_o, msgb);

    // h_u = gelu([nodes|msg] @ Wu1 + bu1)  (bf16, reuses qb)
    gemm_bf16<<<gB, blk, 0, stream>>>(nodes_b, 0, msgb, 0, Wu1T, 2048, bu1, nullptr, nullptr, hub, 2048, 1);
    // updated = h_u @ Wu2 + bu2 + nodes  (fp32 out + bf16 copy, reuses kb)
    gemm_bf16<<<gB, blk, 0, stream>>>(hub, 0, nullptr, 0, Wu2T, 1024, bu2, nodes, upd_o, updb, 1024, 0);
    // h_i = gelu([updated|ctx] @ Wi1 + bi1)  (bf16, reuses vb)
    gemm_bf16<<<gB, blk, 0, stream>>>(updb, 0, updb, 2, Wi1T, 2048, bi1, nullptr, nullptr, hib, 2048, 1);

    // imp logits, softmax+cap+fused, losses
    row_dot_b<<<dim3(7168), blk, 0, stream>>>(hib, Wi2, bi2, il);
    imp_fused_k<<<dim3(1024), blk, 0, stream>>>(il, upd_o, imp_o, fused_o);
    zero_acc<<<1, 64, 0, stream>>>(acc);
    physics_k<<<dim3(1024), blk, 0, stream>>>(upd_o, fused_o, acc);
    finalize_k<<<1, 1, 0, stream>>>(acc, phys_o, align_o);
}

// Round 3
// 597.282 us; speedup vs baseline: 4.9791x; 1.2559x over previous
//
#include <hip/hip_runtime.h>
#include <hip/hip_bf16.h>

// PhysicsGraphFusion: B=1024, N=7, D=1024
// Outputs (flat): fused (B*D), updated (B*N*D), imp (B*N), attn (B*N*N), phys (1), align (1)

typedef __attribute__((ext_vector_type(8))) short bf16x8;
typedef __attribute__((ext_vector_type(4))) float f32x4;

__constant__ float c_adj[49] = {
    1,1,0,0,1,1,1,
    1,1,1,1,1,1,1,
    0,1,1,0,1,0,1,
    0,1,0,1,1,1,1,
    1,1,1,1,1,1,1,
    1,1,0,1,1,1,1,
    1,1,1,1,1,1,1};

__device__ __forceinline__ float gelu_f(float x) {
    return 0.5f * x * (1.0f + erff(x * 0.7071067811865476f));
}
__device__ __forceinline__ float b2f(unsigned short u) {
    unsigned int x = ((unsigned int)u) << 16;
    union { unsigned int i; float f; } c; c.i = x; return c.f;
}
__device__ __forceinline__ unsigned short f2b(float f) {
    __hip_bfloat16 h = __float2bfloat16(f);
    union { __hip_bfloat16 b; unsigned short u; } c; c.b = h; return c.u;
}

__device__ __forceinline__ void gload_lds16(const void* g, void* l) {
    __builtin_amdgcn_global_load_lds(
        (const __attribute__((address_space(1))) unsigned int*)g,
        (__attribute__((address_space(3))) unsigned int*)l, 16, 0, 0);
}

// row mapping: 0: r->r ; 1: r->r*7+6 (ctx rows) ; 2: r->r-r%7+6 (ctx broadcast)
__device__ __forceinline__ int maprow(int r, int mode) {
    if (mode == 1) return r * 7 + 6;
    if (mode == 2) return r - r % 7 + 6;
    return r;
}

// ---------------------------------------------------------------------------
// 128x128-tile bf16 MFMA GEMM. C[M x N] = epi(Acat[M x K] @ WT^T)
// WT = W^T [N x K] bf16 row stride ldw. Acat cols [0,1024) A1, [1024,2048) A2.
// Cb segmented: idx = (c>>10)*segStride + r*1024 + (c&1023).
// ---------------------------------------------------------------------------
__global__ __launch_bounds__(256) void gemm128(
    const unsigned short* __restrict__ A1, int a1Mode,
    const unsigned short* __restrict__ A2, int a2Mode,
    const unsigned short* __restrict__ WT, int ldw,
    const float* __restrict__ bias,
    const float* __restrict__ resid,
    float* __restrict__ Cf,
    unsigned short* __restrict__ Cb, size_t segStride,
    int K, int act)
{
    __shared__ short As[128 * 32];
    __shared__ short Bs[128 * 32];
    const int tid = threadIdx.x;
    const int lane = tid & 63;
    const int w = tid >> 6;
    const int wr = (w >> 1) * 64;
    const int wc = (w & 1) * 64;
    const int row0 = blockIdx.y * 128;
    const int col0 = blockIdx.x * 128;
    const int fr = lane & 15;
    const int fk = (lane >> 4) * 8;

    f32x4 acc[4][4] = {};

    for (int k0 = 0; k0 < K; k0 += 32) {
        const unsigned short* srcA; int mode; int kbase;
        if (k0 < 1024) { srcA = A1; mode = a1Mode; kbase = k0; }
        else           { srcA = A2; mode = a2Mode; kbase = k0 - 1024; }
        #pragma unroll
        for (int rnd = 0; rnd < 2; ++rnd) {
            int c = rnd * 256 + tid;
            int m = c >> 2, kc = (c & 3) * 8;
            int rr = maprow(row0 + m, mode);
            gload_lds16(srcA + (size_t)rr * 1024 + kbase + kc, &As[c * 8]);
        }
        #pragma unroll
        for (int rnd = 0; rnd < 2; ++rnd) {
            int c = rnd * 256 + tid;
            int n = c >> 2, kc = (c & 3) * 8;
            gload_lds16(WT + (size_t)(col0 + n) * ldw + k0 + kc, &Bs[c * 8]);
        }
        __syncthreads();
        bf16x8 af[4], bf_[4];
        #pragma unroll
        for (int i = 0; i < 4; ++i)
            af[i] = *(const bf16x8*)(&As[(wr + i * 16 + fr) * 32 + fk]);
        #pragma unroll
        for (int j = 0; j < 4; ++j)
            bf_[j] = *(const bf16x8*)(&Bs[(wc + j * 16 + fr) * 32 + fk]);
        #pragma unroll
        for (int i = 0; i < 4; ++i)
            #pragma unroll
            for (int j = 0; j < 4; ++j)
                acc[i][j] = __builtin_amdgcn_mfma_f32_16x16x32_bf16(
                    af[i], bf_[j], acc[i][j], 0, 0, 0);
        __syncthreads();
    }

    const int qrow = (lane >> 4) * 4;
    const int qcol = lane & 15;
    #pragma unroll
    for (int i = 0; i < 4; ++i) {
        int rbase = row0 + wr + i * 16 + qrow;
        #pragma unroll
        for (int j = 0; j < 4; ++j) {
            int c = col0 + wc + j * 16 + qcol;
            float bv = bias ? bias[c] : 0.0f;
            int seg = c >> 10, c0 = c & 1023;
            #pragma unroll
            for (int reg = 0; reg < 4; ++reg) {
                int r = rbase + reg;
                float vv = acc[i][j][reg] + bv;
                if (act) vv = gelu_f(vv);
                if (resid) vv += resid[(size_t)r * 1024 + c];
                if (Cf) Cf[(size_t)r * 1024 + c] = vv;
                if (Cb) Cb[(size_t)seg * segStride + (size_t)r * 1024 + c0] = f2b(vv);
            }
        }
    }
}

// ---------------------------------------------------------------------------
// 64x128-tile bf16 MFMA GEMM (more blocks for skinny N). grid: (N/128, M/64)
// Each wave: 64 rows x 32 cols (4x2 frags).
// ---------------------------------------------------------------------------
__global__ __launch_bounds__(256) void gemm64x128(
    const unsigned short* __restrict__ A1, int a1Mode,
    const unsigned short* __restrict__ A2, int a2Mode,
    const unsigned short* __restrict__ WT, int ldw,
    const float* __restrict__ bias,
    const float* __restrict__ resid,
    float* __restrict__ Cf,
    unsigned short* __restrict__ Cb,
    int K, int act)
{
    __shared__ short As[64 * 32];
    __shared__ short Bs[128 * 32];
    const int tid = threadIdx.x;
    const int lane = tid & 63;
    const int w = tid >> 6;
    const int wc = w * 32;
    const int row0 = blockIdx.y * 64;
    const int col0 = blockIdx.x * 128;
    const int fr = lane & 15;
    const int fk = (lane >> 4) * 8;

    f32x4 acc[4][2] = {};

    for (int k0 = 0; k0 < K; k0 += 32) {
        const unsigned short* srcA; int mode; int kbase;
        if (k0 < 1024) { srcA = A1; mode = a1Mode; kbase = k0; }
        else           { srcA = A2; mode = a2Mode; kbase = k0 - 1024; }
        {
            int m = tid >> 2, kc = (tid & 3) * 8;
            int rr = maprow(row0 + m, mode);
            gload_lds16(srcA + (size_t)rr * 1024 + kbase + kc, &As[tid * 8]);
        }
        #pragma unroll
        for (int rnd = 0; rnd < 2; ++rnd) {
            int c = rnd * 256 + tid;
            int n = c >> 2, kc = (c & 3) * 8;
            gload_lds16(WT + (size_t)(col0 + n) * ldw + k0 + kc, &Bs[c * 8]);
        }
        __syncthreads();
        bf16x8 af[4], bf_[2];
        #pragma unroll
        for (int i = 0; i < 4; ++i)
            af[i] = *(const bf16x8*)(&As[(i * 16 + fr) * 32 + fk]);
        #pragma unroll
        for (int j = 0; j < 2; ++j)
            bf_[j] = *(const bf16x8*)(&Bs[(wc + j * 16 + fr) * 32 + fk]);
        #pragma unroll
        for (int i = 0; i < 4; ++i)
            #pragma unroll
            for (int j = 0; j < 2; ++j)
                acc[i][j] = __builtin_amdgcn_mfma_f32_16x16x32_bf16(
                    af[i], bf_[j], acc[i][j], 0, 0, 0);
        __syncthreads();
    }

    const int qrow = (lane >> 4) * 4;
    const int qcol = lane & 15;
    #pragma unroll
    for (int i = 0; i < 4; ++i) {
        int rbase = row0 + i * 16 + qrow;
        #pragma unroll
        for (int j = 0; j < 2; ++j) {
            int c = col0 + wc + j * 16 + qcol;
            float bv = bias ? bias[c] : 0.0f;
            #pragma unroll
            for (int reg = 0; reg < 4; ++reg) {
                int r = rbase + reg;
                float vv = acc[i][j][reg] + bv;
                if (act) vv = gelu_f(vv);
                if (resid) vv += resid[(size_t)r * 1024 + c];
                if (Cf) Cf[(size_t)r * 1024 + c] = vv;
                if (Cb) Cb[(size_t)r * 1024 + c] = f2b(vv);
            }
        }
    }
}

// fp32 -> bf16 elementwise cast
__global__ __launch_bounds__(256) void cast_f2b(
    const float* __restrict__ in, unsigned short* __restrict__ out, int n)
{
    int i = (blockIdx.x * 256 + threadIdx.x) * 4;
    if (i >= n) return;
    float4 v = *(const float4*)(in + i);
    ushort4 o;
    o.x = f2b(v.x); o.y = f2b(v.y); o.z = f2b(v.z); o.w = f2b(v.w);
    *(ushort4*)(out + i) = o;
}

// All weight transposes+casts in one dispatch. grid (32, 64, 9).
__global__ __launch_bounds__(256) void tcast_all(
    const float* __restrict__ Wq, const float* __restrict__ Wk,
    const float* __restrict__ Wv, const float* __restrict__ We1,
    const float* __restrict__ Wu1, const float* __restrict__ Wu2,
    const float* __restrict__ Wi1,
    unsigned short* __restrict__ WT_all, unsigned short* __restrict__ Wu1T,
    unsigned short* __restrict__ Wu2T, unsigned short* __restrict__ Wi1T)
{
    const int z = blockIdx.z;
    const float* src; unsigned short* dst; int R;
    switch (z) {
        case 0: src = Wq;            dst = WT_all;               R = 1024; break;
        case 1: src = Wk;            dst = WT_all + 1024 * 1024; R = 1024; break;
        case 2: src = Wv;            dst = WT_all + 2048 * 1024; R = 1024; break;
        case 3: src = We1;           dst = WT_all + 3072 * 1024; R = 1024; break;
        case 4: src = We1 + 1048576; dst = WT_all + 4096 * 1024; R = 1024; break;
        case 5: src = We1 + 2097152; dst = WT_all + 5120 * 1024; R = 1024; break;
        case 6: src = Wu1;           dst = Wu1T;                 R = 2048; break;
        case 7: src = Wu2;           dst = Wu2T;                 R = 1024; break;
        default: src = Wi1;          dst = Wi1T;                 R = 2048; break;
    }
    const int rt = blockIdx.y * 32;
    if (rt >= R) return;
    const int ct = blockIdx.x * 32;
    __shared__ float t[32][33];
    const int tx = threadIdx.x & 31, ty = threadIdx.x >> 5;
    #pragma unroll
    for (int s = 0; s < 4; ++s)
        t[ty + s * 8][tx] = src[(size_t)(rt + ty + s * 8) * 1024 + ct + tx];
    __syncthreads();
    #pragma unroll
    for (int s = 0; s < 4; ++s)
        dst[(size_t)(ct + ty + s * 8) * R + rt + tx] = f2b(t[tx][ty + s * 8]);
}

// bias_all[5120] = [bq | bk | bv | 0 | 0]
__global__ void build_bias(const float* __restrict__ bq,
                           const float* __restrict__ bk,
                           const float* __restrict__ bv,
                           float* __restrict__ bias_all)
{
    int i = blockIdx.x * 256 + threadIdx.x;
    if (i >= 5120) return;
    int seg = i >> 10, c = i & 1023;
    float v = 0.f;
    if (seg == 0) v = bq[c];
    else if (seg == 1) v = bk[c];
    else if (seg == 2) v = bv[c];
    bias_all[i] = v;
}

// ---------------------------------------------------------------------------
// One block per (b,n): edge MLP + logits + softmax + messages (bf16 in/out)
// msg may alias la (each block reads only its own la row, into regs first).
// ---------------------------------------------------------------------------
__global__ __launch_bounds__(256) void attn_msg_b(
    const unsigned short* __restrict__ q, const unsigned short* __restrict__ k,
    const unsigned short* __restrict__ v,
    const unsigned short* __restrict__ la, const unsigned short* __restrict__ rb,
    const float* __restrict__ cc,
    const float* __restrict__ We2, const float* __restrict__ be2,
    float* __restrict__ attn_out, unsigned short* __restrict__ msg)
{
    const int bn = blockIdx.x;
    const int b = bn / 7, n = bn % 7;
    const int tid = threadIdx.x;
    const int lane = tid & 63, wv = tid >> 6;
    const int d0 = tid * 4;
    __shared__ float red[8];
    __shared__ float sm[7];

    float qv[4], lav[4], ccv[4], wev[4];
    {
        ushort4 q4 = *(const ushort4*)(q + (size_t)bn * 1024 + d0);
        ushort4 l4 = *(const ushort4*)(la + (size_t)bn * 1024 + d0);
        float4 c4 = *(const float4*)(cc + (size_t)b * 1024 + d0);
        float4 w4 = *(const float4*)(We2 + d0);
        qv[0] = b2f(q4.x); qv[1] = b2f(q4.y); qv[2] = b2f(q4.z); qv[3] = b2f(q4.w);
        lav[0] = b2f(l4.x); lav[1] = b2f(l4.y); lav[2] = b2f(l4.z); lav[3] = b2f(l4.w);
        ccv[0] = c4.x; ccv[1] = c4.y; ccv[2] = c4.z; ccv[3] = c4.w;
        wev[0] = w4.x; wev[1] = w4.y; wev[2] = w4.z; wev[3] = w4.w;
    }
    for (int m = 0; m < 7; ++m) {
        ushort4 k4 = *(const ushort4*)(k  + (size_t)(b * 7 + m) * 1024 + d0);
        ushort4 r4 = *(const ushort4*)(rb + (size_t)(b * 7 + m) * 1024 + d0);
        float s1 = qv[0] * b2f(k4.x) + qv[1] * b2f(k4.y)
                 + qv[2] * b2f(k4.z) + qv[3] * b2f(k4.w);
        float s2 = gelu_f(lav[0] + b2f(r4.x) + ccv[0]) * wev[0]
                 + gelu_f(lav[1] + b2f(r4.y) + ccv[1]) * wev[1]
                 + gelu_f(lav[2] + b2f(r4.z) + ccv[2]) * wev[2]
                 + gelu_f(lav[3] + b2f(r4.w) + ccv[3]) * wev[3];
        #pragma unroll
        for (int off = 32; off > 0; off >>= 1) {
            s1 += __shfl_down(s1, off);
            s2 += __shfl_down(s2, off);
        }
        if (lane == 0) { red[wv * 2] = s1; red[wv * 2 + 1] = s2; }
        __syncthreads();
        if (tid == 0) {
            float d1 = red[0] + red[2] + red[4] + red[6];
            float d2 = red[1] + red[3] + red[5] + red[7];
            sm[m] = d1 * (1.0f / 32.0f) + d2 + be2[0]
                  + (c_adj[n * 7 + m] - 1.0f) * 10000.0f;
        }
        __syncthreads();
    }
    if (tid == 0) {
        float mx = sm[0];
        #pragma unroll
        for (int m = 1; m < 7; ++m) mx = fmaxf(mx, sm[m]);
        float e[7], s = 0.f;
        #pragma unroll
        for (int m = 0; m < 7; ++m) { e[m] = expf(sm[m] - mx); s += e[m]; }
        float inv = 1.0f / s;
        #pragma unroll
        for (int m = 0; m < 7; ++m) {
            float wgt = e[m] * inv;
            sm[m] = wgt;
            attn_out[(size_t)bn * 7 + m] = wgt;
        }
    }
    __syncthreads();
    float wr_[7];
    #pragma unroll
    for (int m = 0; m < 7; ++m) wr_[m] = sm[m];
    float s0 = 0.f, s1 = 0.f, s2 = 0.f, s3 = 0.f;
    #pragma unroll
    for (int m = 0; m < 7; ++m) {
        ushort4 v4 = *(const ushort4*)(v + (size_t)(b * 7 + m) * 1024 + d0);
        s0 += wr_[m] * b2f(v4.x); s1 += wr_[m] * b2f(v4.y);
        s2 += wr_[m] * b2f(v4.z); s3 += wr_[m] * b2f(v4.w);
    }
    ushort4 o;
    o.x = f2b(s0); o.y = f2b(s1); o.z = f2b(s2); o.w = f2b(s3);
    *(ushort4*)(msg + (size_t)bn * 1024 + d0) = o;
}

// imp_logits[r] = dot(H[r,:], w2) + b2[0]   (H bf16)
__global__ __launch_bounds__(256) void row_dot_b(
    const unsigned short* __restrict__ H, const float* __restrict__ w2,
    const float* __restrict__ b2, float* __restrict__ out)
{
    const int r = blockIdx.x;
    const int tid = threadIdx.x;
    const int lane = tid & 63, wv = tid >> 6;
    __shared__ float red[4];
    const int d0 = tid * 4;
    ushort4 h4 = *(const ushort4*)(H + (size_t)r * 1024 + d0);
    float4 w4 = *(const float4*)(w2 + d0);
    float s = b2f(h4.x) * w4.x + b2f(h4.y) * w4.y
            + b2f(h4.z) * w4.z + b2f(h4.w) * w4.w;
    #pragma unroll
    for (int off = 32; off > 0; off >>= 1) s += __shfl_down(s, off);
    if (lane == 0) red[wv] = s;
    __syncthreads();
    if (tid == 0) out[r] = red[0] + red[1] + red[2] + red[3] + b2[0];
}

// per-b: softmax over N, cap/redistribute, imp; fused = sum_n imp*updated
__global__ __launch_bounds__(256) void imp_fused_k(
    const float* __restrict__ logits, const float* __restrict__ upd,
    float* __restrict__ imp_out, float* __restrict__ fused_out)
{
    const int b = blockIdx.x;
    const int tid = threadIdx.x;
    __shared__ float w[7];
    if (tid == 0) {
        float l[7], e[7];
        float mx = -1e30f;
        for (int i = 0; i < 7; ++i) { l[i] = logits[b * 7 + i]; mx = fmaxf(mx, l[i]); }
        float s = 0.f;
        for (int i = 0; i < 7; ++i) { e[i] = expf(l[i] - mx); s += e[i]; }
        float inv = 1.0f / s;
        float imp[7];
        for (int i = 0; i < 7; ++i) imp[i] = e[i] * inv;
        const float cap[7] = {1.f, 1.f, 1.f, 0.26f, 1.f, 1.f, 0.24f};
        const float fr[7]  = {1.f, 1.f, 1.f, 0.f,   1.f, 1.f, 0.f};
        float capped[7], capsum = 0.f, fmass = 0.f;
        for (int i = 0; i < 7; ++i) {
            capped[i] = fminf(imp[i], cap[i]);
            capsum += capped[i];
            fmass += imp[i] * fr[i];
        }
        float residual = fmaxf(1.0f - capsum, 0.0f);
        float redis[7], rs = 0.f;
        for (int i = 0; i < 7; ++i) {
            float fs = (fmass > 1e-6f) ? imp[i] * fr[i] / fmaxf(fmass, 1e-6f)
                                       : fr[i] * 0.2f;
            redis[i] = capped[i] + fs * residual;
            rs += redis[i];
        }
        float invr = 1.0f / fmaxf(rs, 1e-6f);
        for (int i = 0; i < 7; ++i) {
            float wi = redis[i] * invr;
            w[i] = wi;
            imp_out[b * 7 + i] = wi;
        }
    }
    __syncthreads();
    float wr[7];
    #pragma unroll
    for (int i = 0; i < 7; ++i) wr[i] = w[i];
    #pragma unroll
    for (int j = 0; j < 4; ++j) {
        int d = tid + j * 256;
        float s = 0.f;
        #pragma unroll
        for (int nn2 = 0; nn2 < 7; ++nn2)
            s += wr[nn2] * upd[(size_t)(b * 7 + nn2) * 1024 + d];
        fused_out[(size_t)b * 1024 + d] = s;
    }
}

__global__ void zero_acc(float* a) { if (threadIdx.x < 4) a[threadIdx.x] = 0.f; }

__global__ __launch_bounds__(256) void physics_k(
    const float* __restrict__ upd, const float* __restrict__ fused,
    float* __restrict__ accums)
{
    const int b = blockIdx.x;
    const int tid = threadIdx.x;
    const int lane = tid & 63, wv = tid >> 6;
    __shared__ float u[7][1024];
    __shared__ float f[1024];
    __shared__ float wred[4][36];
    for (int idx = tid; idx < 7 * 1024; idx += 256)
        u[idx >> 10][idx & 1023] = upd[(size_t)b * 7168 + idx];
    for (int d = tid; d < 1024; d += 256)
        f[d] = fused[(size_t)b * 1024 + d];
    __syncthreads();

    float vals[36];
    #pragma unroll
    for (int i = 0; i < 36; ++i) vals[i] = 0.f;
    for (int d = tid; d < 1024; d += 256) {
        float x[7];
        #pragma unroll
        for (int n = 0; n < 7; ++n) x[n] = u[n][d];
        float fv = f[d];
        int idx = 0;
        #pragma unroll
        for (int n = 0; n < 7; ++n) {
            #pragma unroll
            for (int m = n; m < 7; ++m) vals[idx++] += x[n] * x[m];
        }
        #pragma unroll
        for (int n = 0; n < 7; ++n) vals[28 + n] += x[n] * fv;
        vals[35] += fv * fv;
    }
    #pragma unroll
    for (int i = 0; i < 36; ++i) {
        float s = vals[i];
        #pragma unroll
        for (int off = 32; off > 0; off >>= 1) s += __shfl_down(s, off);
        if (lane == 0) wred[wv][i] = s;
    }
    __syncthreads();
    if (tid == 0) {
        float tv[36];
        for (int i = 0; i < 36; ++i)
            tv[i] = wred[0][i] + wred[1][i] + wred[2][i] + wred[3][i];
        auto didx = [](int n, int m) -> int {
            if (n > m) { int t = n; n = m; m = t; }
            return n * 7 - n * (n - 1) / 2 + (m - n);
        };
        float norms[7];
        for (int n = 0; n < 7; ++n) norms[n] = sqrtf(tv[didx(n, n)]);
        float e = 0.f, nl = 0.f;
        for (int n = 0; n < 7; ++n)
            for (int m = 0; m < 7; ++m) {
                float cos_ = tv[didx(n, m)] / fmaxf(norms[n] * norms[m], 1e-8f);
                float adj = c_adj[n * 7 + m];
                e += (1.0f - cos_) * adj;
                if (adj == 0.0f && n != m) nl += fmaxf(cos_ - 0.35f, 0.0f);
            }
        float fnorm = sqrtf(tv[35]);
        float al = 0.f;
        for (int n = 0; n < 7; ++n) {
            float cosn = tv[28 + n] /
                         (fmaxf(norms[n], 1e-12f) * fmaxf(fnorm, 1e-12f));
            al += 1.0f - cosn;
        }
        atomicAdd(&accums[0], e);
        atomicAdd(&accums[1], nl);
        atomicAdd(&accums[2], al);
    }
}

__global__ void finalize_k(const float* __restrict__ a,
                           float* __restrict__ phys_o,
                           float* __restrict__ align_o)
{
    phys_o[0]  = a[0] / 41.0f + 0.5f * (a[1] / 8.0f);
    align_o[0] = a[2] * (1.0f / 7168.0f);
}

extern "C" void kernel_launch(void* const* d_in, const int* in_sizes, int n_in,
                              void* d_out, int out_size, void* d_ws, size_t ws_size,
                              hipStream_t stream)
{
    const float* nodes = (const float*)d_in[0];
    const float* Wq  = (const float*)d_in[1];
    const float* bq  = (const float*)d_in[2];
    const float* Wk  = (const float*)d_in[3];
    const float* bk  = (const float*)d_in[4];
    const float* Wv  = (const float*)d_in[5];
    const float* bv  = (const float*)d_in[6];
    const float* We1 = (const float*)d_in[7];
    const float* be1 = (const float*)d_in[8];
    const float* We2 = (const float*)d_in[9];
    const float* be2 = (const float*)d_in[10];
    const float* Wu1 = (const float*)d_in[11];
    const float* bu1 = (const float*)d_in[12];
    const float* Wu2 = (const float*)d_in[13];
    const float* bu2 = (const float*)d_in[14];
    const float* Wi1 = (const float*)d_in[15];
    const float* bi1 = (const float*)d_in[16];
    const float* Wi2 = (const float*)d_in[17];
    const float* bi2 = (const float*)d_in[18];

    float* out = (float*)d_out;
    float* fused_o = out;                            // 1,048,576
    float* upd_o   = out + 1048576;                  // 7,340,032
    float* imp_o   = out + 1048576 + 7340032;        // 7,168
    float* attn_o  = imp_o + 7168;                   // 50,176
    float* phys_o  = attn_o + 50176;                 // 1
    float* align_o = phys_o + 1;                     // 1

    const size_t BIG = 7340032;   // B*N*D
    const size_t MEG = 1048576;   // D*D
    char* p = (char*)d_ws;
    unsigned short* nodes_b = (unsigned short*)p; p += BIG * 2;
    unsigned short* qb      = (unsigned short*)p; p += BIG * 2;   // seg 0; reused: h_u
    unsigned short* kb      = (unsigned short*)p; p += BIG * 2;   // seg 1; reused: upd_b
    unsigned short* vb      = (unsigned short*)p; p += BIG * 2;   // seg 2; reused: h_i
    unsigned short* lab     = (unsigned short*)p; p += BIG * 2;   // seg 3; reused: msg
    unsigned short* rbb     = (unsigned short*)p; p += BIG * 2;   // seg 4
    unsigned short* WT_all  = (unsigned short*)p; p += (size_t)6144 * 1024 * 2;
    unsigned short* Wu1T    = (unsigned short*)p; p += 2 * MEG * 2;
    unsigned short* Wu2T    = (unsigned short*)p; p += MEG * 2;
    unsigned short* Wi1T    = (unsigned short*)p; p += 2 * MEG * 2;
    float* bias_all = (float*)p; p += 5120 * 4;
    float* ccf = (float*)p; p += MEG * 4;
    float* il  = (float*)p; p += 7168 * 4;
    float* acc = (float*)p; p += 4 * 4;
    unsigned short* msgb = lab;   // alias: safe (see attn_msg_b)
    unsigned short* hub  = qb;
    unsigned short* updb = kb;
    unsigned short* hib  = vb;

    dim3 blk(256);

    // prep
    cast_f2b<<<dim3(7168), blk, 0, stream>>>(nodes, nodes_b, 7340032);
    tcast_all<<<dim3(32, 64, 9), blk, 0, stream>>>(Wq, Wk, Wv, We1, Wu1, Wu2, Wi1,
                                                   WT_all, Wu1T, Wu2T, Wi1T);
    build_bias<<<dim3(20), blk, 0, stream>>>(bq, bk, bv, bias_all);

    // fused q|k|v|la|rb : N=5120, segmented bf16 out into qb..rbb
    gemm128<<<dim3(40, 56), blk, 0, stream>>>(
        nodes_b, 0, nullptr, 0, WT_all, 1024, bias_all, nullptr,
        nullptr, qb, BIG, 1024, 0);

    // cc = nodes[:,-1] @ Wc + be1 (fp32 out), WcT at WT_all row 5120
    gemm64x128<<<dim3(8, 16), blk, 0, stream>>>(
        nodes_b, 1, nullptr, 0, WT_all + (size_t)5120 * 1024, 1024, be1, nullptr,
        ccf, nullptr, 1024, 0);

    // attention + messages (msg overwrites la)
    attn_msg_b<<<dim3(7168), blk, 0, stream>>>(qb, kb, vb, lab, rbb, ccf, We2, be2,
                                               attn_o, msgb);

    // h_u = gelu([nodes|msg] @ Wu1 + bu1)
    gemm64x128<<<dim3(8, 112), blk, 0, stream>>>(
        nodes_b, 0, msgb, 0, Wu1T, 2048, bu1, nullptr, nullptr, hub, 2048, 1);
    // updated = h_u @ Wu2 + bu2 + nodes (fp32 out + bf16 copy)
    gemm64x128<<<dim3(8, 112), blk, 0, stream>>>(
        hub, 0, nullptr, 0, Wu2T, 1024, bu2, nodes, upd_o, updb, 1024, 0);
    // h_i = gelu([updated|ctx] @ Wi1 + bi1)
    gemm64x128<<<dim3(8, 112), blk, 0, stream>>>(
        updb, 0, updb, 2, Wi1T, 2048, bi1, nullptr, nullptr, hib, 2048, 1);

    // tail
    row_dot_b<<<dim3(7168), blk, 0, stream>>>(hib, Wi2, bi2, il);
    imp_fused_k<<<dim3(1024), blk, 0, stream>>>(il, upd_o, imp_o, fused_o);
    zero_acc<<<1, 64, 0, stream>>>(acc);
    physics_k<<<dim3(1024), blk, 0, stream>>>(upd_o, fused_o, acc);
    finalize_k<<<1, 1, 0, stream>>>(acc, phys_o, align_o);
}